// Round 9
// baseline (180.485 us; speedup 1.0000x reference)
//
#include <hip/hip_runtime.h>
#include <hip/hip_bf16.h>

#define BB 8
#define LL 4096
#define NCH 8192
#define IDIM 256
#define KDIM 512
#define ODIM 512
#define NDIR 6
#define TOT (BB * LL)  // 32768
#define MT 128         // m-tile rows

typedef short short8 __attribute__((ext_vector_type(8)));
typedef float floatx4 __attribute__((ext_vector_type(4)));

// ws layout (ints):
//   [0..7]               cnt per dir (atomic cursors)
//   [64 .. 64+6T)        idx_by_slot  (slot -> token), slot = d*TOT + pos
//   [64+6T .. 64+12T)    rows_by_slot (r0 | r1<<16)
//   [WBF_OFF ...)        bf16 W copy (3.1 MB)
#define IDX_OFF 64
#define ROWS_OFF (64 + NDIR * TOT)
#define WBF_OFF (64 + 2 * NDIR * TOT)
#define W_ELEMS (NDIR * ODIM * KDIM)  // 1,572,864
#define N_W8 (W_ELEMS / 8)            // 196,608
#define SCAT_BLK (TOT / 256)          // 128
#define CVTW_BLK (N_W8 / 256)         // 768

__device__ inline void async_copy16(const void* g, void* l) {
  __builtin_amdgcn_global_load_lds(
      (const __attribute__((address_space(1))) void*)g,
      (__attribute__((address_space(3))) void*)l, 16, 0, 0);
}

// ---- Kernel 1 (fused prep): scatter buckets | cvt W to bf16 ----
__global__ __launch_bounds__(256) void prep_kernel(
    const int* __restrict__ vec, const int* __restrict__ child_l,
    const int* __restrict__ child_r, const int* __restrict__ drev,
    const int* __restrict__ dmap, const float* __restrict__ W,
    int* __restrict__ ws) {
  int bid = blockIdx.x;
  int tid = threadIdx.x;
  if (bid < SCAT_BLK) {
    __shared__ int lcnt[8];
    __shared__ int gbase[8];
    if (tid < 8) lcnt[tid] = 0;
    __syncthreads();
    int t = bid * 256 + tid;
    int l = t & (LL - 1);
    int v = vec[t];
    int dir = dmap[v] & 7;
    int sw = drev[v];
    int cl = child_l[l];
    int cr = child_r[l];
    int r0 = sw ? cr : cl;  // first half of x
    int r1 = sw ? cl : cr;  // second half
    int pos = atomicAdd(&lcnt[dir], 1);
    __syncthreads();
    if (tid < 8) gbase[tid] = lcnt[tid] ? atomicAdd(&ws[tid], lcnt[tid]) : 0;
    __syncthreads();
    int slot = dir * TOT + gbase[dir] + pos;
    ws[IDX_OFF + slot] = t;
    ws[ROWS_OFF + slot] = r0 | (r1 << 16);
  } else {
    int gid = (bid - SCAT_BLK) * 256 + tid;  // < N_W8
    __hip_bfloat16* W_bf = (__hip_bfloat16*)(ws + WBF_OFF);
    const floatx4* s = (const floatx4*)W;
    floatx4 a = s[2 * gid];
    floatx4 b = s[2 * gid + 1];
    union { short8 v; __hip_bfloat16 h[8]; } u;
    u.h[0] = __float2bfloat16(a[0]); u.h[1] = __float2bfloat16(a[1]);
    u.h[2] = __float2bfloat16(a[2]); u.h[3] = __float2bfloat16(a[3]);
    u.h[4] = __float2bfloat16(b[0]); u.h[5] = __float2bfloat16(b[1]);
    u.h[6] = __float2bfloat16(b[2]); u.h[7] = __float2bfloat16(b[3]);
    ((short8*)W_bf)[gid] = u.v;
  }
}

// ---- Kernel 2: grouped GEMM, r4 skeleton, A staged as FP32 ----
// 128x128 tile, BK=64, single-buffered 2-barrier chunks (empirically best
// r4-r8). A: fp32 rows of `last` staged via global_load_lds (32 KB/chunk),
// converted to bf16 at fragment read. B: bf16 W (16 KB/chunk). 48 KB LDS.
// Swizzles (16B units, applied on the global-source side):
//   A (16 units/row): stored_u = u ^ (row & 15)
//   B (8 units/row):  stored_u = u ^ (row & 7)
// Both give <=2-way bank aliasing per 16-lane phase (free, m136).
__global__ __launch_bounds__(256) void gemm_kernel(
    const float* __restrict__ last, const float* __restrict__ bias,
    const float* __restrict__ alpha_m, const int* __restrict__ ws,
    float* __restrict__ out) {
  __shared__ float Als[128 * 64];             // fp32, 32 KB
  __shared__ __hip_bfloat16 Bls[128 * 64];    // bf16, 16 KB

  // tile -> (dir, m_base) from per-dir counts (128-aligned tile ranges)
  const int mt = blockIdx.y;
  const int nt = blockIdx.x;
  int d = -1, count = 0, m_base = 0;
  {
    int tb = 0;
    for (int dd = 0; dd < NDIR; ++dd) {
      int c = ws[dd];
      int ntile = (c + MT - 1) / MT;
      if (mt < tb + ntile) { d = dd; count = c; m_base = (mt - tb) * MT; break; }
      tb += ntile;
    }
  }
  if (d < 0) return;

  const __hip_bfloat16* W_bf = (const __hip_bfloat16*)(ws + WBF_OFF);
  const int* idx = ws + IDX_OFF + d * TOT;
  const int* rows = ws + ROWS_OFF + d * TOT;

  const int tid = threadIdx.x;
  const int wave = __builtin_amdgcn_readfirstlane(tid >> 6);
  const int lane = tid & 63;
  const int lane15 = lane & 15;
  const int quad = lane >> 4;
  const int wm = wave >> 1;
  const int wn = wave & 1;
  const int n_blk = nt * 128;

  // ---- A staging descriptors: 8 instrs/thread, 4 rows each (fp32) ----
  // instr i: local row sr = wave*32 + i*4 + (lane>>4), unit = lane&15.
  int aoff0[8], aoff1[8], aldsbase[8];
#pragma unroll
  for (int i = 0; i < 8; ++i) {
    int sr = wave * 32 + i * 4 + (lane >> 4);
    aldsbase[i] = (wave * 32 + i * 4) * 64;  // fp32 elems, wave-uniform
    int lr = m_base + sr;
    if (lr >= count) lr = count - 1;
    int t = idx[lr] & (TOT - 1);
    int rr = rows[lr];
    int b = t >> 12;  // L=4096
    int r0 = rr & (NCH - 1);
    int r1 = (rr >> 16) & (NCH - 1);
    int su = ((lane & 15) ^ (sr & 15)) * 4;  // swizzled unit -> fp32 elems
    aoff0[i] = (b * NCH + r0) * IDIM + su;
    aoff1[i] = (b * NCH + r1) * IDIM + su;
  }
  // ---- B staging descriptors: 4 instrs/thread, 8 rows each (bf16) ----
  const __hip_bfloat16* bp[4];
  int bldsbase[4];
#pragma unroll
  for (int i = 0; i < 4; ++i) {
    int sr = wave * 32 + i * 8 + (lane >> 3);
    bldsbase[i] = (wave * 32 + i * 8) * 64;  // bf16 elems, wave-uniform
    int xu = ((lane & 7) ^ (sr & 7)) * 8;    // swizzled unit -> bf16 elems
    bp[i] = W_bf + (long long)(d * ODIM + n_blk + sr) * KDIM + xu;
  }

  floatx4 acc[4][4] = {};
  const int rx = lane15;       // A frag row swizzle key (row&15)
  const int lx = lane15 & 7;   // B frag row swizzle key (row&7)

#pragma unroll
  for (int kt = 0; kt < 8; ++kt) {
    __syncthreads();  // previous chunk's LDS reads complete before overwrite
    {
      const int ko = (kt & 3) * 64;  // fp32 elems into the 256-elem row half
      const float* abase = last + ko;
#pragma unroll
      for (int i = 0; i < 8; ++i) {
        const float* ga = abase + (kt < 4 ? aoff0[i] : aoff1[i]);
        async_copy16(ga, &Als[aldsbase[i]]);
      }
#pragma unroll
      for (int i = 0; i < 4; ++i)
        async_copy16(bp[i] + kt * 64, &Bls[bldsbase[i]]);
    }
    __syncthreads();  // staging visible (vmcnt(0) drain before barrier)

#pragma unroll
    for (int s = 0; s < 2; ++s) {
      short8 a[4], b[4];
#pragma unroll
      for (int i = 0; i < 4; ++i) {
        const int arow = (wm * 64 + i * 16 + lane15) * 64;
        const int u0 = s * 8 + quad * 2;
        floatx4 f0 = *(const floatx4*)&Als[arow + ((u0 ^ rx) * 4)];
        floatx4 f1 = *(const floatx4*)&Als[arow + (((u0 + 1) ^ rx) * 4)];
        union { short8 v; __hip_bfloat16 h[8]; } u;
        u.h[0] = __float2bfloat16(f0[0]); u.h[1] = __float2bfloat16(f0[1]);
        u.h[2] = __float2bfloat16(f0[2]); u.h[3] = __float2bfloat16(f0[3]);
        u.h[4] = __float2bfloat16(f1[0]); u.h[5] = __float2bfloat16(f1[1]);
        u.h[6] = __float2bfloat16(f1[2]); u.h[7] = __float2bfloat16(f1[3]);
        a[i] = u.v;
      }
      const int xcol = ((quad + 4 * s) ^ lx) * 8;
#pragma unroll
      for (int j = 0; j < 4; ++j)
        b[j] = *(const short8*)&Bls[(wn * 64 + j * 16 + lane15) * 64 + xcol];
#pragma unroll
      for (int i = 0; i < 4; ++i)
#pragma unroll
        for (int j = 0; j < 4; ++j)
          acc[i][j] = __builtin_amdgcn_mfma_f32_16x16x32_bf16(a[i], b[j], acc[i][j], 0, 0, 0);
    }
  }

  // ---- epilogue: bias + leaky relu, scatter rows by token ----
  const float alpha = alpha_m[d];
  float bj[4];
#pragma unroll
  for (int j = 0; j < 4; ++j)
    bj[j] = bias[d * ODIM + n_blk + wn * 64 + j * 16 + lane15];

#pragma unroll
  for (int i = 0; i < 4; ++i) {
#pragma unroll
    for (int reg = 0; reg < 4; ++reg) {
      int row_id = m_base + wm * 64 + i * 16 + quad * 4 + reg;
      if (row_id >= count) continue;
      int t = idx[row_id] & (TOT - 1);
      float* orow = out + (long long)t * ODIM + n_blk + wn * 64;
#pragma unroll
      for (int j = 0; j < 4; ++j) {
        float y = acc[i][j][reg] + bj[j];
        y = y > 0.f ? y : alpha * y;
        orow[j * 16 + lane15] = y;
      }
    }
  }
}

extern "C" void kernel_launch(void* const* d_in, const int* in_sizes, int n_in,
                              void* d_out, int out_size, void* d_ws, size_t ws_size,
                              hipStream_t stream) {
  const float* last = (const float*)d_in[0];
  const float* W = (const float*)d_in[1];
  const float* bias = (const float*)d_in[2];
  const float* alpha = (const float*)d_in[3];
  const int* child_l = (const int*)d_in[4];
  const int* child_r = (const int*)d_in[5];
  const int* vec = (const int*)d_in[6];
  const int* drev = (const int*)d_in[7];
  const int* dmap = (const int*)d_in[8];

  int* ws = (int*)d_ws;

  hipMemsetAsync(ws, 0, 32, stream);
  prep_kernel<<<SCAT_BLK + CVTW_BLK, 256, 0, stream>>>(
      vec, child_l, child_r, drev, dmap, W, ws);
  dim3 grid(ODIM / 128, TOT / MT + NDIR, 1);
  gemm_kernel<<<grid, 256, 0, stream>>>(last, bias, alpha, ws, (float*)d_out);
}